// Round 6
// baseline (309.791 us; speedup 1.0000x reference)
//
#include <hip/hip_runtime.h>

// Aggregator: B=8192, H=10, N=25, F=128, D=256 (half=128). Rows = B*H = 81920.
// out[row][0:128]   = relu(x_self[row]          @ w_self  + bias[0:128])
// out[row][128:256] = relu(mean_n(x_neigh[row]) @ w_neigh + bias[128:256])
//
// R6 discriminator: two-pass. Pass 1 is a PURE streamer (no LDS/barrier/compute
// phase) writing raw means into out[:,128:256]; pass 2 reads them back and does
// both projections (R2's register-tile structure). If pass 1 streams at ~6 TB/s
// the fused kernels were structure-limited (H1); if total ~255us the read path
// itself caps near 5 TB/s (H2) and R0 was already at roofline.

// ---------------- Pass 1: neighbor mean (pure stream) ----------------
// One item per thread: item = row*32 + v. 25 loads grouped 13+12 for MLP
// within a ~96-VGPR budget (4 blocks/CU).
__global__ __launch_bounds__(256, 4) void mean_kernel(
    const float* __restrict__ x_neigh,  // [rows][25][128]
    float* __restrict__ out,            // [rows][256]; means -> cols 128:256
    int nitems)
{
    const int item = blockIdx.x * 256 + threadIdx.x;
    if (item >= nitems) return;
    const int v = item & 31;            // float4 column
    const size_t row = (size_t)(item >> 5);

    const float4* xn4 = (const float4*)x_neigh;
    const size_t base = row * 800 + v;  // float4 units; row stride 25*32

    float4 st[13];
    #pragma unroll
    for (int n = 0; n < 13; ++n) st[n] = xn4[base + n * 32];
    float4 a0 = st[0], a1 = st[1], a2 = st[2], a3 = st[3];
    #pragma unroll
    for (int n = 4; n < 13; ++n) {
        float4 t = st[n];
        if ((n & 3) == 0) { a0.x += t.x; a0.y += t.y; a0.z += t.z; a0.w += t.w; }
        else if ((n & 3) == 1) { a1.x += t.x; a1.y += t.y; a1.z += t.z; a1.w += t.w; }
        else if ((n & 3) == 2) { a2.x += t.x; a2.y += t.y; a2.z += t.z; a2.w += t.w; }
        else { a3.x += t.x; a3.y += t.y; a3.z += t.z; a3.w += t.w; }
    }
    float4 st2[12];
    #pragma unroll
    for (int n = 0; n < 12; ++n) st2[n] = xn4[base + (13 + n) * 32];
    #pragma unroll
    for (int n = 0; n < 12; ++n) {
        float4 t = st2[n];
        if ((n & 3) == 0) { a0.x += t.x; a0.y += t.y; a0.z += t.z; a0.w += t.w; }
        else if ((n & 3) == 1) { a1.x += t.x; a1.y += t.y; a1.z += t.z; a1.w += t.w; }
        else if ((n & 3) == 2) { a2.x += t.x; a2.y += t.y; a2.z += t.z; a2.w += t.w; }
        else { a3.x += t.x; a3.y += t.y; a3.z += t.z; a3.w += t.w; }
    }
    float4 a;
    const float inv = 1.0f / 25.0f;
    a.x = (a0.x + a1.x + a2.x + a3.x) * inv;
    a.y = (a0.y + a1.y + a2.y + a3.y) * inv;
    a.z = (a0.z + a1.z + a2.z + a3.z) * inv;
    a.w = (a0.w + a1.w + a2.w + a3.w) * inv;

    // out row = 64 float4; neigh half starts at float4 index 32
    ((float4*)out)[row * 64 + 32 + v] = a;
}

// ---------------- Pass 2: both projections (R2 register-tile) ----------------
#define RPB 16

__device__ __forceinline__ void fma4(float4& a, float s, const float4& b) {
    a.x = fmaf(s, b.x, a.x);
    a.y = fmaf(s, b.y, a.y);
    a.z = fmaf(s, b.z, a.z);
    a.w = fmaf(s, b.w, a.w);
}

__global__ __launch_bounds__(256, 4) void proj_kernel(
    const float* __restrict__ x_self,   // [rows][128]
    const float* __restrict__ w_neigh,  // [128][128]
    const float* __restrict__ w_self,   // [128][128]
    const float* __restrict__ bias,     // [256]
    float* __restrict__ out,            // [rows][256]; cols 128:256 hold means
    int rows)
{
    __shared__ float xs[RPB][128];
    __shared__ float ag[RPB][128];

    const int tid  = threadIdx.x;
    const int row0 = blockIdx.x * RPB;

    // stage x_self rows and mean rows (from out) into LDS
    {
        const float4* xs4 = (const float4*)x_self;
        const float4* o4  = (const float4*)out;
        #pragma unroll
        for (int it = 0; it < 2; ++it) {
            const int item = tid + it * 256;
            const int r = item >> 5;
            const int v = item & 31;
            const size_t row = (size_t)(row0 + r);
            *(float4*)&xs[r][v * 4] = xs4[row * 32 + v];
            *(float4*)&ag[r][v * 4] = o4[row * 64 + 32 + v];  // read-before-write
        }
    }
    __syncthreads();

    // 4x4 register tile: sel = half, cols c0..c0+3, rows rg..rg+3
    const int sel = tid >> 7;
    const int u   = tid & 127;
    const int c0  = (u & 31) * 4;
    const int rg  = (u >> 5) * 4;

    const float* __restrict__ w = sel ? w_neigh : w_self;
    const float (*vec)[128] = sel ? ag : xs;

    float4 acc[4];
    #pragma unroll
    for (int r = 0; r < 4; ++r) acc[r] = make_float4(0.f, 0.f, 0.f, 0.f);

    for (int f4 = 0; f4 < 32; ++f4) {
        const float4 w0 = *(const float4*)&w[(f4 * 4 + 0) * 128 + c0];
        const float4 w1 = *(const float4*)&w[(f4 * 4 + 1) * 128 + c0];
        const float4 w2 = *(const float4*)&w[(f4 * 4 + 2) * 128 + c0];
        const float4 w3 = *(const float4*)&w[(f4 * 4 + 3) * 128 + c0];
        #pragma unroll
        for (int r = 0; r < 4; ++r) {
            const float4 xv = *(const float4*)&vec[rg + r][f4 * 4];
            fma4(acc[r], xv.x, w0);
            fma4(acc[r], xv.y, w1);
            fma4(acc[r], xv.z, w2);
            fma4(acc[r], xv.w, w3);
        }
    }

    const float4 b4 = *(const float4*)&bias[sel * 128 + c0];
    #pragma unroll
    for (int r = 0; r < 4; ++r) {
        float4 o;
        o.x = fmaxf(acc[r].x + b4.x, 0.f);
        o.y = fmaxf(acc[r].y + b4.y, 0.f);
        o.z = fmaxf(acc[r].z + b4.z, 0.f);
        o.w = fmaxf(acc[r].w + b4.w, 0.f);
        *(float4*)&out[(size_t)(row0 + rg + r) * 256 + sel * 128 + c0] = o;
    }
}

extern "C" void kernel_launch(void* const* d_in, const int* in_sizes, int n_in,
                              void* d_out, int out_size, void* d_ws, size_t ws_size,
                              hipStream_t stream) {
    const float* x_self  = (const float*)d_in[0];
    const float* x_neigh = (const float*)d_in[1];
    const float* w_neigh = (const float*)d_in[2];
    const float* w_self  = (const float*)d_in[3];
    const float* bias    = (const float*)d_in[4];
    float* out = (float*)d_out;

    const int rows   = in_sizes[0] / 128;   // 81920
    const int nitems = rows * 32;           // 2,621,440
    const int b1     = (nitems + 255) / 256;   // 10240
    const int b2     = rows / RPB;             // 5120

    mean_kernel<<<b1, 256, 0, stream>>>(x_neigh, out, nitems);
    proj_kernel<<<b2, 256, 0, stream>>>(x_self, w_neigh, w_self, bias, out, rows);
}

// Round 7
// 214.824 us; speedup vs baseline: 1.4421x; 1.4421x over previous
//
#include <hip/hip_runtime.h>

// Aggregator: B=8192, H=10, N=25, F=128, D=256 (half=128). Rows = B*H = 81920.
// out[row][0:128]   = relu(x_self[row]          @ w_self  + bias[0:128])
// out[row][128:256] = relu(mean_n(x_neigh[row]) @ w_neigh + bias[128:256])
//
// R7: exact R0 structure (best of 6 tried: 240us) + NON-TEMPORAL loads for the
// single-use x streams and nt stores for out. Tests whether L1/L2/L3
// allocate-on-miss churn (1 GB single-use stream through 256 MB L3) is the
// ~25% gap to the read roofline. Weights/bias stay cached (reused).

#define RPB 16  // rows per block

typedef float f32x4 __attribute__((ext_vector_type(4)));

__device__ __forceinline__ f32x4 ntload(const f32x4* p) {
    return __builtin_nontemporal_load(p);
}

__global__ __launch_bounds__(256, 4) void agg_fused_kernel(
    const float* __restrict__ x_self,   // [rows][128]
    const float* __restrict__ x_neigh,  // [rows][25][128]
    const float* __restrict__ w_neigh,  // [128][128]
    const float* __restrict__ w_self,   // [128][128]
    const float* __restrict__ bias,     // [256]
    float* __restrict__ out,            // [rows][256]
    int rows)
{
    __shared__ float xs[RPB][128];
    __shared__ float ag[RPB][128];

    const int tid  = threadIdx.x;
    const int row0 = blockIdx.x * RPB;

    // ---- Phase 1: stage x_self rows and neighbor-mean rows into LDS ----
    // Item space: RPB rows * 32 float4-cols = 512 items; 256 threads * 2 items.
    {
        const f32x4* xs4 = (const f32x4*)x_self;
        const f32x4* xn4 = (const f32x4*)x_neigh;
        #pragma unroll
        for (int it = 0; it < 2; ++it) {
            const int item = tid + it * 256;
            const int r = item >> 5;      // 0..15
            const int v = item & 31;      // float4 column
            const size_t row = (size_t)(row0 + r);

            f32x4 s = ntload(&xs4[row * 32 + v]);
            *(f32x4*)&xs[r][v * 4] = s;

            f32x4 acc = ntload(&xn4[row * 800 + v]);
            const size_t base = row * 800 + v;  // float4 units; row stride 25*32
            #pragma unroll
            for (int n = 1; n < 25; ++n) {
                f32x4 t = ntload(&xn4[base + (size_t)n * 32]);
                acc += t;
            }
            acc *= (1.0f / 25.0f);
            *(f32x4*)&ag[r][v * 4] = acc;
        }
    }
    __syncthreads();

    // ---- Phase 2: projections (R0 mapping) ----
    // thread t: output column (t & 127), half (t >> 7): 0 = self, 1 = neigh.
    const int col = tid & 127;
    const int sel = tid >> 7;
    const float* __restrict__ w = sel ? w_neigh : w_self;
    const float (*vec)[128] = sel ? ag : xs;

    float acc[RPB];
    #pragma unroll
    for (int r = 0; r < RPB; ++r) acc[r] = 0.f;

    for (int f4 = 0; f4 < 32; ++f4) {
        // 4 weight scalars per iteration; coalesced across the wave (col = lane).
        const float w0 = w[(f4 * 4 + 0) * 128 + col];
        const float w1 = w[(f4 * 4 + 1) * 128 + col];
        const float w2 = w[(f4 * 4 + 2) * 128 + col];
        const float w3 = w[(f4 * 4 + 3) * 128 + col];
        #pragma unroll
        for (int r = 0; r < RPB; ++r) {
            float4 v = *(const float4*)&vec[r][f4 * 4];  // wave-uniform broadcast
            acc[r] = fmaf(v.x, w0, acc[r]);
            acc[r] = fmaf(v.y, w1, acc[r]);
            acc[r] = fmaf(v.z, w2, acc[r]);
            acc[r] = fmaf(v.w, w3, acc[r]);
        }
    }

    const float b = bias[sel * 128 + col];
    #pragma unroll
    for (int r = 0; r < RPB; ++r) {
        const float o = fmaxf(acc[r] + b, 0.f);
        __builtin_nontemporal_store(
            o, &out[(size_t)(row0 + r) * 256 + sel * 128 + col]);
    }
}

extern "C" void kernel_launch(void* const* d_in, const int* in_sizes, int n_in,
                              void* d_out, int out_size, void* d_ws, size_t ws_size,
                              hipStream_t stream) {
    const float* x_self  = (const float*)d_in[0];
    const float* x_neigh = (const float*)d_in[1];
    const float* w_neigh = (const float*)d_in[2];
    const float* w_self  = (const float*)d_in[3];
    const float* bias    = (const float*)d_in[4];
    float* out = (float*)d_out;

    const int rows = in_sizes[0] / 128;        // B*H = 81920
    const int blocks = (rows + RPB - 1) / RPB; // 5120

    agg_fused_kernel<<<blocks, 256, 0, stream>>>(
        x_self, x_neigh, w_neigh, w_self, bias, out, rows);
}